// Round 1
// baseline (367.421 us; speedup 1.0000x reference)
//
#include <hip/hip_runtime.h>

#define N_ROWS 8192
#define N_COLS 10000
#define SCALE  64.0f

// Single fused kernel: 1 block x 1024 threads (16 waves on one CU).
// Each thread: 8 contiguous labels (2x int4 = 32B/lane, coalescing sweet
// spot), 8 scattered gather loads issued back-to-back (ILP -> one HBM
// latency round-trip), then wave shuffle-reduce + LDS cross-wave reduce.
// One launch, no workspace, no partial-buffer HBM round trip.
__global__ __launch_bounds__(1024) void center_fused(
    const float* __restrict__ feature,
    const int*   __restrict__ label,
    float*       __restrict__ out) {
    const int t = threadIdx.x;
    const int base = t * 8;   // rows base..base+7, always in range (1024*8=8192)

    const int4 l0 = ((const int4*)label)[2 * t];
    const int4 l1 = ((const int4*)label)[2 * t + 1];

    // Issue all 8 independent gathers before any use (compiler keeps them
    // in flight together; sum only after all loads are issued).
    float v0 = feature[(size_t)(base + 0) * N_COLS + l0.x];
    float v1 = feature[(size_t)(base + 1) * N_COLS + l0.y];
    float v2 = feature[(size_t)(base + 2) * N_COLS + l0.z];
    float v3 = feature[(size_t)(base + 3) * N_COLS + l0.w];
    float v4 = feature[(size_t)(base + 4) * N_COLS + l1.x];
    float v5 = feature[(size_t)(base + 5) * N_COLS + l1.y];
    float v6 = feature[(size_t)(base + 6) * N_COLS + l1.z];
    float v7 = feature[(size_t)(base + 7) * N_COLS + l1.w];

    float s = ((v0 + v1) + (v2 + v3)) + ((v4 + v5) + (v6 + v7));

    // Wave-64 shuffle reduction.
    #pragma unroll
    for (int off = 32; off > 0; off >>= 1)
        s += __shfl_down(s, off, 64);

    __shared__ float wsum[16];
    if ((t & 63) == 0) wsum[t >> 6] = s;
    __syncthreads();

    if (t < 16) {
        float x = wsum[t];
        #pragma unroll
        for (int off = 8; off > 0; off >>= 1)
            x += __shfl_down(x, off, 16);
        if (t == 0)
            out[0] = 2.0f - 2.0f * (x / SCALE) / (float)N_ROWS;
    }
}

extern "C" void kernel_launch(void* const* d_in, const int* in_sizes, int n_in,
                              void* d_out, int out_size, void* d_ws, size_t ws_size,
                              hipStream_t stream) {
    const float* feature = (const float*)d_in[0];
    const int*   label   = (const int*)d_in[1];
    float*       out     = (float*)d_out;

    center_fused<<<1, 1024, 0, stream>>>(feature, label, out);
}

// Round 2
// 349.613 us; speedup vs baseline: 1.0509x; 1.0509x over previous
//
#include <hip/hip_runtime.h>

#define N_ROWS 8192
#define N_COLS 10000
#define SCALE  64.0f
#define NBLK   128   // 128 blocks x 64 threads = one row per thread

// Kernel 1: one wave per block, one gathered row element per thread.
// 128 blocks spread across CUs -> 64 outstanding HBM misses per CU, all
// issued together -> ~one memory round-trip total (label load -> gather).
// (Round-1 lesson: fusing to 1 block serialized 8192 misses through one
// CU's miss queue -> +18 us. Latency hiding here REQUIRES many CUs.)
__global__ __launch_bounds__(64) void center_partial(
    const float* __restrict__ feature,
    const int*   __restrict__ label,
    float*       __restrict__ partial) {
    const int i = blockIdx.x * 64 + threadIdx.x;   // 0..8191, always in range
    const int l = label[i];                        // coalesced 256B/wave
    float v = feature[(size_t)i * N_COLS + (size_t)l];  // 1 cacheline/lane

    #pragma unroll
    for (int off = 32; off > 0; off >>= 1)
        v += __shfl_down(v, off, 64);

    if (threadIdx.x == 0) partial[blockIdx.x] = v;
}

// Kernel 2: single wave, 2 partials/lane, shuffle-reduce, write the loss.
// No LDS, no __syncthreads -- minimum possible epilogue.
__global__ __launch_bounds__(64) void center_final(
    const float* __restrict__ partial,
    float*       __restrict__ out) {
    const int tid = threadIdx.x;
    float v = partial[tid] + partial[tid + 64];

    #pragma unroll
    for (int off = 32; off > 0; off >>= 1)
        v += __shfl_down(v, off, 64);

    if (tid == 0)
        out[0] = 2.0f - 2.0f * (v / SCALE) / (float)N_ROWS;
}

extern "C" void kernel_launch(void* const* d_in, const int* in_sizes, int n_in,
                              void* d_out, int out_size, void* d_ws, size_t ws_size,
                              hipStream_t stream) {
    const float* feature = (const float*)d_in[0];
    const int*   label   = (const int*)d_in[1];
    float*       out     = (float*)d_out;
    float*       partial = (float*)d_ws;   // 128 floats, fully overwritten

    center_partial<<<NBLK, 64, 0, stream>>>(feature, label, partial);
    center_final<<<1, 64, 0, stream>>>(partial, out);
}